// Round 9
// baseline (272.460 us; speedup 1.0000x reference)
//
#include <hip/hip_runtime.h>

// ---------------------------------------------------------------------------
// PolyDecoder via SYMMETRY COLLAPSE: out = A_mono[4096 x 1287] @ Wc^T + (bias
// folded), where A_mono are multiset monomials of z (deg<=5) and Wc sums W
// over all ordered tuples mapping to the same multiset. 29x fewer FLOPs than
// the ordered-Kronecker GEMM.
//
// Canonical multiset order: degree-major (d=0..5), within degree lex order on
// sorted non-decreasing tuples (j1<=...<=jd). DOFF = {0,1,9,45,165,495},
// total 1287, padded to 1344 = 42 K32-steps.
// Rank of sorted tuple: DOFF[d] + sum_t sum_{v=L..g_t-1} C(rest+7-v, rest).
//
// Pipeline: memset(Wc) -> prep(collapse + featgen) -> gemm_small.
// ---------------------------------------------------------------------------

#define K_TOT 37449
#define SPAD 42                     // padded K32 steps
#define NRANK_PAD (SPAD * 32)       // 1344
#define WC_BYTES (NRANK_PAD * 64 * 4)
#define AT_OFF WC_BYTES             // 344064, 64-aligned

typedef _Float16 half8 __attribute__((ext_vector_type(8)));
typedef float f32x4 __attribute__((ext_vector_type(4)));

__device__ __constant__ int CNK12[12][5] = {
    {1,0,0,0,0},{1,1,0,0,0},{1,2,1,0,0},{1,3,3,1,0},{1,4,6,4,1},
    {1,5,10,10,5},{1,6,15,20,15},{1,7,21,35,35},{1,8,28,56,70},
    {1,9,36,84,126},{1,10,45,120,210},{1,11,55,165,330}};

#define CE(x, y) { int lo_ = min(x, y), hi_ = max(x, y); x = lo_; y = hi_; }

// blocks [0,74): collapse W -> Wc (f32, MFMA-fragment layout, atomics)
// blocks [74,138): featgen -> At (f16, fragment-tiled A)
__global__ __launch_bounds__(512) void prep(const float* __restrict__ W,
                                            const float* __restrict__ bias,
                                            const float* __restrict__ z,
                                            float* __restrict__ Wc,
                                            _Float16* __restrict__ At) {
    __shared__ _Float16 zls[8][64];
    int tid = threadIdx.x;
    int b   = blockIdx.x;

    if (b < 74) {
        // ---------------- collapse ----------------
        int k = b * 512 + tid;
        if (k >= K_TOT) return;
        int d, k0 = 0;
        if (k == 0)        { d = 0; }
        else if (k < 9)    { d = 1; k0 = k - 1; }
        else if (k < 73)   { d = 2; k0 = k - 9; }
        else if (k < 585)  { d = 3; k0 = k - 73; }
        else if (k < 4681) { d = 4; k0 = k - 585; }
        else               { d = 5; k0 = k - 4681; }
        int g0 = 7, g1 = 7, g2 = 7, g3 = 7, g4 = 7;
        if (d >= 1) { g0 = k0 & 7; k0 >>= 3; }
        if (d >= 2) { g1 = k0 & 7; k0 >>= 3; }
        if (d >= 3) { g2 = k0 & 7; k0 >>= 3; }
        if (d >= 4) { g3 = k0 & 7; k0 >>= 3; }
        if (d == 5) { g4 = k0 & 7; }
        // sort ascending (9-CE network); pads (7) land at the end
        CE(g0,g1); CE(g3,g4); CE(g2,g4); CE(g2,g3); CE(g1,g4);
        CE(g0,g3); CE(g0,g2); CE(g1,g3); CE(g1,g2);
        // rank within canonical order
        int rank = (d == 0) ? 0 : (d == 1) ? 1 : (d == 2) ? 9
                 : (d == 3) ? 45 : (d == 4) ? 165 : 495;
        int L = 0;
        if (d > 0) { int r_ = d-1; for (int v = L; v < g0; ++v) rank += CNK12[r_+7-v][r_]; L = g0; }
        if (d > 1) { int r_ = d-2; for (int v = L; v < g1; ++v) rank += CNK12[r_+7-v][r_]; L = g1; }
        if (d > 2) { int r_ = d-3; for (int v = L; v < g2; ++v) rank += CNK12[r_+7-v][r_]; L = g2; }
        if (d > 3) { int r_ = d-4; for (int v = L; v < g3; ++v) rank += CNK12[r_+7-v][r_]; L = g3; }
        if (d > 4) { rank += max(0, g4 - L); }
        // fragment address: (rank rk, n) -> ((rk/32*4 + n/16)*64 + (rk%32/8)*16 + n%16)*8 + rk%8
        int q = rank >> 5, pos = rank & 31;
        int fb = (q * 4 * 64 + (pos >> 3) * 16) * 8 + (pos & 7);
#pragma unroll
        for (int nt = 0; nt < 4; ++nt)
#pragma unroll
            for (int l = 0; l < 16; ++l) {
                int n = nt * 16 + l;
                float val = W[(size_t)n * K_TOT + k];
                if (k == 0) val += bias[n];
                unsafeAtomicAdd(Wc + fb + (nt * 64 + l) * 8, val);
            }
    } else {
        // ---------------- featgen ----------------
        int sb   = b - 74;
        int w    = tid >> 6;           // wave = first digit j1
        int lane = tid & 63;
        size_t m = (size_t)sb * 64 + lane;
        if (w == 0) {
            const float* zp = z + m * 8;
            float4 za = *(const float4*)zp;
            float4 zb = *(const float4*)(zp + 4);
            zls[0][lane] = (_Float16)za.x; zls[1][lane] = (_Float16)za.y;
            zls[2][lane] = (_Float16)za.z; zls[3][lane] = (_Float16)za.w;
            zls[4][lane] = (_Float16)zb.x; zls[5][lane] = (_Float16)zb.y;
            zls[6][lane] = (_Float16)zb.z; zls[7][lane] = (_Float16)zb.w;
        }
        __syncthreads();

        // subtree start offsets for first digit w
        int st2 = 9, st3 = 45, st4 = 165, st5 = 495;
        for (int v = 0; v < w; ++v) {
            st2 += CNK12[8 - v][1];
            st3 += CNK12[9 - v][2];
            st4 += CNK12[10 - v][3];
            st5 += CNK12[11 - v][4];
        }

        _Float16* atm = At + m * 32;   // + (r>>5)*131072 + (r&31)
        auto stA = [&](int r, _Float16 v) {
            atm[(size_t)(r >> 5) * 131072 + (r & 31)] = v;
        };

        _Float16 p1 = zls[w][lane];
        if (w == 0) stA(0, (_Float16)1.0f);   // degree-0 constant
        stA(1 + w, p1);                        // degree 1
        int r2 = st2, r3 = st3, r4 = st4, r5 = st5;
        for (int bq = w; bq < 8; ++bq) {
            _Float16 p2 = p1 * zls[bq][lane];
            stA(r2++, p2);
            for (int cq = bq; cq < 8; ++cq) {
                _Float16 p3 = p2 * zls[cq][lane];
                stA(r3++, p3);
                for (int eq = cq; eq < 8; ++eq) {
                    _Float16 p4 = p3 * zls[eq][lane];
                    stA(r4++, p4);
                    for (int fq = eq; fq < 8; ++fq)
                        stA(r5++, p4 * zls[fq][lane]);
                }
            }
        }
    }
}

// 256 blocks x 1 wave: 16 rows x 64 cols x 42 steps. B from Wc (f32, L2-hot),
// converted in-register; A streamed from At. Direct stores, no reduction.
__global__ __launch_bounds__(64) void gemm_small(const _Float16* __restrict__ At,
                                                 const float* __restrict__ Wc,
                                                 float* __restrict__ out) {
    int lane = threadIdx.x;
    int l16  = lane & 15, quad = lane >> 4;
    int m0   = blockIdx.x * 16;

    const _Float16* ap = At + (size_t)(m0 + l16) * 32 + quad * 8;
    const float*    bp = Wc + lane * 8;

    f32x4 acc[4];
#pragma unroll
    for (int nt = 0; nt < 4; ++nt) acc[nt] = (f32x4){0.f, 0.f, 0.f, 0.f};

    auto loadA = [&](int s) { return *(const half8*)(ap + (size_t)s * 131072); };
    auto loadB = [&](int s, f32x4* Bf) {
#pragma unroll
        for (int nt = 0; nt < 4; ++nt) {
            const float* p = bp + (size_t)(s * 4 + nt) * 512;
            Bf[nt * 2]     = *(const f32x4*)p;
            Bf[nt * 2 + 1] = *(const f32x4*)(p + 4);
        }
    };
    auto compute = [&](half8 A, const f32x4* Bf) {
#pragma unroll
        for (int nt = 0; nt < 4; ++nt) {
            half8 hb;
#pragma unroll
            for (int j = 0; j < 4; ++j) {
                hb[j]     = (_Float16)Bf[nt * 2][j];
                hb[j + 4] = (_Float16)Bf[nt * 2 + 1][j];
            }
            acc[nt] = __builtin_amdgcn_mfma_f32_16x16x32_f16(A, hb, acc[nt], 0, 0, 0);
        }
    };

    half8 A0 = loadA(0), A1 = loadA(1);
    f32x4 B0[8], B1[8];
    loadB(0, B0);
    loadB(1, B1);
    for (int s = 0; s < SPAD; s += 2) {
        compute(A0, B0);
        if (s + 2 < SPAD) { A0 = loadA(s + 2); loadB(s + 2, B0); }
        compute(A1, B1);
        if (s + 3 < SPAD) { A1 = loadA(s + 3); loadB(s + 3, B1); }
    }

    // C/D layout: col = lane&15 (n within tile), row = quad*4 + reg
#pragma unroll
    for (int nt = 0; nt < 4; ++nt) {
        int col = nt * 16 + l16;
#pragma unroll
        for (int r = 0; r < 4; ++r)
            out[(size_t)(m0 + quad * 4 + r) * 64 + col] = acc[nt][r];
    }
}

extern "C" void kernel_launch(void* const* d_in, const int* in_sizes, int n_in,
                              void* d_out, int out_size, void* d_ws, size_t ws_size,
                              hipStream_t stream) {
    (void)in_sizes; (void)n_in; (void)out_size; (void)ws_size;
    const float* z = (const float*)d_in[0];
    const float* W = (const float*)d_in[1];
    const float* b = (const float*)d_in[2];
    float* out = (float*)d_out;

    float*     Wc = (float*)d_ws;                        // 344,064 B
    _Float16*  At = (_Float16*)((char*)d_ws + AT_OFF);   // 11,010,048 B

    hipMemsetAsync(Wc, 0, WC_BYTES, stream);
    hipLaunchKernelGGL(prep, dim3(138), dim3(512), 0, stream, W, b, z, Wc, At);
    hipLaunchKernelGGL(gemm_small, dim3(256), dim3(64), 0, stream, At, Wc, out);
}

// Round 10
// 172.987 us; speedup vs baseline: 1.5750x; 1.5750x over previous
//
#include <hip/hip_runtime.h>

// ---------------------------------------------------------------------------
// PolyDecoder via SYMMETRY COLLAPSE (atomics-free dataflow):
//   out[4096,64] = A_mono[4096 x 1287] @ Wc^T   (bias folded into rank 0)
// where A_mono are multiset monomials of z (deg<=5) and Wc sums W over all
// ordered Kronecker tuples mapping to the same multiset (29x FLOP reduction).
//
// Canonical multiset order: degree-major, lex on sorted tuples.
// DOFF = {0,1,9,45,165,495}, NRANK=1287, padded to 1344 = 42 K32 steps.
//
// Pipeline: memset(Wcf+cnt) -> transpose_w (W->WT[k][n]) + rank_scatter
//           (k -> perm[rank][.]) -> collapse (gather, wave/rank, coalesced)
//           -> feat_gemm (featgen into LDS + 42-step MFMA GEMM, fused).
// ---------------------------------------------------------------------------

#define K_TOT 37449
#define SPAD 42
#define NRANK 1287
#define WCF_BYTES (SPAD * 4 * 64 * 8 * 2)          // 172032 B (f16 B-fragments)
#define CNT_OFF   WCF_BYTES
#define CNT_BYTES 5248                              // >= 1287*4
#define PERM_OFF  (CNT_OFF + CNT_BYTES)             // 177280
#define PERM_BYTES (NRANK * 120 * 4)                // 617760
#define WT_OFF    795136                            // aligned past perm

typedef _Float16 half8 __attribute__((ext_vector_type(8)));
typedef float f32x4 __attribute__((ext_vector_type(4)));

__device__ __constant__ int CNK12[12][5] = {
    {1,0,0,0,0},{1,1,0,0,0},{1,2,1,0,0},{1,3,3,1,0},{1,4,6,4,1},
    {1,5,10,10,5},{1,6,15,20,15},{1,7,21,35,35},{1,8,28,56,70},
    {1,9,36,84,126},{1,10,45,120,210},{1,11,55,165,330}};

#define CE(x, y) { int lo_ = min(x, y), hi_ = max(x, y); x = lo_; y = hi_; }

// ---- W[64][K] -> WT[K][64], LDS-tiled, coalesced both sides ----
__global__ __launch_bounds__(256) void transpose_w(const float* __restrict__ W,
                                                   float* __restrict__ WT) {
    __shared__ float t[64][65];
    int tid = threadIdx.x, lane = tid & 63, nq = tid >> 6;
    int kb = blockIdx.x * 64;
#pragma unroll
    for (int r = 0; r < 16; ++r) {
        int n = nq * 16 + r;
        int k = kb + lane;
        t[n][lane] = (k < K_TOT) ? W[(size_t)n * K_TOT + k] : 0.f;
    }
    __syncthreads();
#pragma unroll
    for (int i = 0; i < 16; ++i) {
        int kk = nq * 16 + i;
        int k  = kb + kk;
        if (k < K_TOT) WT[(size_t)k * 64 + lane] = t[lane][kk];
    }
}

// ---- thread per k: rank of sorted digit multiset; append to perm list ----
__global__ __launch_bounds__(512) void rank_scatter(int* __restrict__ cnt,
                                                    int* __restrict__ perm) {
    int k = blockIdx.x * 512 + threadIdx.x;
    if (k >= K_TOT) return;
    int d, k0 = 0;
    if (k == 0)        { d = 0; }
    else if (k < 9)    { d = 1; k0 = k - 1; }
    else if (k < 73)   { d = 2; k0 = k - 9; }
    else if (k < 585)  { d = 3; k0 = k - 73; }
    else if (k < 4681) { d = 4; k0 = k - 585; }
    else               { d = 5; k0 = k - 4681; }
    int g0 = 7, g1 = 7, g2 = 7, g3 = 7, g4 = 7;
    if (d >= 1) { g0 = k0 & 7; k0 >>= 3; }
    if (d >= 2) { g1 = k0 & 7; k0 >>= 3; }
    if (d >= 3) { g2 = k0 & 7; k0 >>= 3; }
    if (d >= 4) { g3 = k0 & 7; k0 >>= 3; }
    if (d == 5) { g4 = k0 & 7; }
    CE(g0,g1); CE(g3,g4); CE(g2,g4); CE(g2,g3); CE(g1,g4);
    CE(g0,g3); CE(g0,g2); CE(g1,g3); CE(g1,g2);
    int rank = (d == 0) ? 0 : (d == 1) ? 1 : (d == 2) ? 9
             : (d == 3) ? 45 : (d == 4) ? 165 : 495;
    int L = 0;
    if (d > 0) { int r_ = d-1; for (int v = L; v < g0; ++v) rank += CNK12[r_+7-v][r_]; L = g0; }
    if (d > 1) { int r_ = d-2; for (int v = L; v < g1; ++v) rank += CNK12[r_+7-v][r_]; L = g1; }
    if (d > 2) { int r_ = d-3; for (int v = L; v < g2; ++v) rank += CNK12[r_+7-v][r_]; L = g2; }
    if (d > 3) { int r_ = d-4; for (int v = L; v < g3; ++v) rank += CNK12[r_+7-v][r_]; L = g3; }
    if (d > 4) { rank += max(0, g4 - L); }
    int pos = atomicAdd(cnt + rank, 1);            // int atomic, 1287 counters
    perm[rank * 120 + pos] = k;
}

// ---- wave per rank: gather-sum WT rows (coalesced), write f16 B-fragment ----
__global__ __launch_bounds__(256) void collapse(const float* __restrict__ WT,
                                                const float* __restrict__ bias,
                                                const int* __restrict__ cnt,
                                                const int* __restrict__ perm,
                                                _Float16* __restrict__ Wcf) {
    int lane = threadIdx.x & 63;
    int rank = blockIdx.x * 4 + (threadIdx.x >> 6);
    if (rank >= NRANK) return;
    int nper = cnt[rank];
    const int* pl = perm + rank * 120;
    float acc = (rank == 0) ? bias[lane] : 0.f;
    for (int i = 0; i < nper; ++i) {
        int k = pl[i];                               // wave-uniform
        acc += WT[(size_t)k * 64 + lane];            // coalesced 256 B
    }
    // B-fragment: element (s,nt,lane',j) = B[nt*16+(lane'&15)][s*32+(lane'>>4)*8+j]
    int s = rank >> 5, kk = rank & 31;
    int nt = lane >> 4, nl = lane & 15;
    Wcf[((size_t)(s * 4 + nt) * 64 + (kk >> 3) * 16 + nl) * 8 + (kk & 7)] =
        (_Float16)acc;
}

// ---- fused: featgen (16 samples -> LDS monomials) + 42-step MFMA GEMM ----
__global__ __launch_bounds__(128) void feat_gemm(const float* __restrict__ z,
                                                 const _Float16* __restrict__ Wcf,
                                                 float* __restrict__ out) {
    __shared__ _Float16 A[16][1352];   // pitch 1352: 16B-aligned rows
    __shared__ _Float16 zls[8][17];
    int tid = threadIdx.x;
    int m0  = blockIdx.x * 16;

    {   // z: 16 samples x 8 dims, coalesced
        int smp = tid >> 3, dd = tid & 7;
        zls[dd][smp] = (_Float16)z[(size_t)(m0 + smp) * 8 + dd];
    }
    __syncthreads();

    {   // featgen: sample = tid&15, subtree first-digit w = tid>>4
        int smp = tid & 15, w = tid >> 4;
        _Float16* Am = &A[smp][0];
        for (int r = NRANK + w; r < SPAD * 32; r += 8) Am[r] = (_Float16)0.f;
        int st2 = 9, st3 = 45, st4 = 165, st5 = 495;
        for (int v = 0; v < w; ++v) {
            st2 += CNK12[8 - v][1];
            st3 += CNK12[9 - v][2];
            st4 += CNK12[10 - v][3];
            st5 += CNK12[11 - v][4];
        }
        _Float16 p1 = zls[w][smp];
        if (w == 0) Am[0] = (_Float16)1.f;
        Am[1 + w] = p1;
        int r2 = st2, r3 = st3, r4 = st4, r5 = st5;
        for (int bq = w; bq < 8; ++bq) {
            _Float16 p2 = p1 * zls[bq][smp];
            Am[r2++] = p2;
            for (int cq = bq; cq < 8; ++cq) {
                _Float16 p3 = p2 * zls[cq][smp];
                Am[r3++] = p3;
                for (int eq = cq; eq < 8; ++eq) {
                    _Float16 p4 = p3 * zls[eq][smp];
                    Am[r4++] = p4;
                    for (int fq = eq; fq < 8; ++fq)
                        Am[r5++] = p4 * zls[fq][smp];
                }
            }
        }
    }
    __syncthreads();

    // GEMM: 2 waves; wave wv: 16 rows x cols [wv*32, wv*32+32)
    int lane = tid & 63, wv = tid >> 6;
    int l16 = lane & 15, quad = lane >> 4;
    const _Float16* Arow  = &A[l16][quad * 8];
    const _Float16* Bbase = Wcf + (size_t)(2 * wv) * 512 + (size_t)lane * 8;

    f32x4 acc0 = (f32x4){0.f,0.f,0.f,0.f}, acc1 = (f32x4){0.f,0.f,0.f,0.f};
    auto ldA = [&](int s) { return *(const half8*)(Arow + s * 32); };
    auto ldB = [&](int s, half8* B) {
        B[0] = *(const half8*)(Bbase + (size_t)s * 2048);
        B[1] = *(const half8*)(Bbase + (size_t)s * 2048 + 512);
    };

    half8 Ab[4], Bb[4][2];
#pragma unroll
    for (int i = 0; i < 4; ++i) { Ab[i] = ldA(i); ldB(i, Bb[i]); }
#pragma unroll
    for (int s = 0; s < SPAD; ++s) {
        half8 a = Ab[s & 3], b0 = Bb[s & 3][0], b1 = Bb[s & 3][1];
        if (s + 4 < SPAD) { Ab[s & 3] = ldA(s + 4); ldB(s + 4, Bb[s & 3]); }
        acc0 = __builtin_amdgcn_mfma_f32_16x16x32_f16(a, b0, acc0, 0, 0, 0);
        acc1 = __builtin_amdgcn_mfma_f32_16x16x32_f16(a, b1, acc1, 0, 0, 0);
    }

    // C/D: col = lane&15, row = quad*4 + reg
#pragma unroll
    for (int nt = 0; nt < 2; ++nt) {
        f32x4 acc = nt ? acc1 : acc0;
        int col = wv * 32 + nt * 16 + l16;
#pragma unroll
        for (int r = 0; r < 4; ++r)
            out[(size_t)(m0 + quad * 4 + r) * 64 + col] = acc[r];
    }
}

extern "C" void kernel_launch(void* const* d_in, const int* in_sizes, int n_in,
                              void* d_out, int out_size, void* d_ws, size_t ws_size,
                              hipStream_t stream) {
    (void)in_sizes; (void)n_in; (void)out_size; (void)ws_size;
    const float* z = (const float*)d_in[0];
    const float* W = (const float*)d_in[1];
    const float* b = (const float*)d_in[2];
    float* out = (float*)d_out;

    _Float16* Wcf = (_Float16*)d_ws;
    int*      cnt = (int*)((char*)d_ws + CNT_OFF);
    int*      perm = (int*)((char*)d_ws + PERM_OFF);
    float*    WT  = (float*)((char*)d_ws + WT_OFF);   // 9,586,944 B

    hipMemsetAsync(d_ws, 0, PERM_OFF, stream);        // Wcf + cnt
    hipLaunchKernelGGL(transpose_w, dim3((K_TOT + 63) / 64), dim3(256), 0,
                       stream, W, WT);
    hipLaunchKernelGGL(rank_scatter, dim3((K_TOT + 511) / 512), dim3(512), 0,
                       stream, cnt, perm);
    hipLaunchKernelGGL(collapse, dim3((NRANK + 3) / 4), dim3(256), 0,
                       stream, WT, b, cnt, perm, Wcf);
    hipLaunchKernelGGL(feat_gemm, dim3(4096 / 16), dim3(128), 0,
                       stream, z, Wcf, out);
}

// Round 11
// 109.837 us; speedup vs baseline: 2.4806x; 1.5749x over previous
//
#include <hip/hip_runtime.h>

// ---------------------------------------------------------------------------
// PolyDecoder via SYMMETRY COLLAPSE (atomics-light, ILP-deep dataflow):
//   out[4096,64] = A_mono[4096 x 1287] @ Wc^T   (bias folded into rank 0)
// A_mono = multiset monomials of z (deg<=5); Wc sums W over ordered tuples
// per multiset (29x FLOP reduction vs the ordered-Kronecker GEMM).
//
// Canonical order: degree-major, lex on sorted tuples. DOFF={0,1,9,45,165,495},
// NRANK=1287, padded to 1344 = 42 K32 steps. Digits packed 5x4 bits, pad=8
// (z~[8] := 1.0).
//
// Pipeline: memset(Wcf+cnt) -> prep (transpose W->WT | rank/perm/digs)
//           -> collapse (gather, 2 waves/rank, 4-deep ILP, scalar perm loads)
//           -> feat_gemm (lane-parallel featgen via digs + 42-step MFMA GEMM).
// ---------------------------------------------------------------------------

#define K_TOT 37449
#define SPAD 42
#define NRANK 1287
#define NRPAD (SPAD * 32)                    // 1344
#define WCF_BYTES (SPAD * 4 * 64 * 8 * 2)    // 172032 (f16 B-fragments)
#define CNT_OFF   WCF_BYTES
#define CNT_BYTES 5248
#define PERM_OFF  (CNT_OFF + CNT_BYTES)      // 177280
#define DIGS_OFF  795136                     // past perm (617760)
#define WT_OFF    800512                     // past digs (5376); 16B-aligned

#define TB 586                               // transpose blocks (64 k each)
#define RB 147                               // rank blocks (256 k each)

typedef _Float16 half8 __attribute__((ext_vector_type(8)));
typedef float f32x4 __attribute__((ext_vector_type(4)));

__device__ __constant__ int CNK12[12][5] = {
    {1,0,0,0,0},{1,1,0,0,0},{1,2,1,0,0},{1,3,3,1,0},{1,4,6,4,1},
    {1,5,10,10,5},{1,6,15,20,15},{1,7,21,35,35},{1,8,28,56,70},
    {1,9,36,84,126},{1,10,45,120,210},{1,11,55,165,330}};

#define CE(x, y) { int lo_ = min(x, y), hi_ = max(x, y); x = lo_; y = hi_; }

// Dual-role: blocks [0,TB) transpose W[64][K]->WT[K][64]; blocks [TB,TB+RB)
// compute rank per k, append k to perm[rank], canonical k writes digs[rank].
__global__ __launch_bounds__(256) void prep(const float* __restrict__ W,
                                            float* __restrict__ WT,
                                            int* __restrict__ cnt,
                                            int* __restrict__ perm,
                                            int* __restrict__ digs) {
    __shared__ float t[64][65];
    int tid = threadIdx.x;
    int b   = blockIdx.x;

    if (b < TB) {
        int lane = tid & 63, nq = tid >> 6;
        int kb = b * 64;
#pragma unroll
        for (int r = 0; r < 16; ++r) {
            int n = nq * 16 + r;
            int k = kb + lane;
            t[n][lane] = (k < K_TOT) ? W[(size_t)n * K_TOT + k] : 0.f;
        }
        __syncthreads();
#pragma unroll
        for (int i = 0; i < 16; ++i) {
            int kk = nq * 16 + i;
            int k  = kb + kk;
            if (k < K_TOT) WT[(size_t)k * 64 + lane] = t[lane][kk];
        }
        return;
    }

    int k = (b - TB) * 256 + tid;
    if (k >= K_TOT) return;
    int d, k0 = 0;
    if (k == 0)        { d = 0; }
    else if (k < 9)    { d = 1; k0 = k - 1; }
    else if (k < 73)   { d = 2; k0 = k - 9; }
    else if (k < 585)  { d = 3; k0 = k - 73; }
    else if (k < 4681) { d = 4; k0 = k - 585; }
    else               { d = 5; k0 = k - 4681; }
    int g0 = 8, g1 = 8, g2 = 8, g3 = 8, g4 = 8;     // pad = 8
    if (d >= 1) { g0 = k0 & 7; k0 >>= 3; }
    if (d >= 2) { g1 = k0 & 7; k0 >>= 3; }
    if (d >= 3) { g2 = k0 & 7; k0 >>= 3; }
    if (d >= 4) { g3 = k0 & 7; k0 >>= 3; }
    if (d == 5) { g4 = k0 & 7; }
    int o0 = g0, o1 = g1, o2 = g2, o3 = g3, o4 = g4;
    CE(g0,g1); CE(g3,g4); CE(g2,g4); CE(g2,g3); CE(g1,g4);
    CE(g0,g3); CE(g0,g2); CE(g1,g3); CE(g1,g2);
    int rank = (d == 0) ? 0 : (d == 1) ? 1 : (d == 2) ? 9
             : (d == 3) ? 45 : (d == 4) ? 165 : 495;
    int L = 0;
    if (d > 0) { int r_ = d-1; for (int v = L; v < g0; ++v) rank += CNK12[r_+7-v][r_]; L = g0; }
    if (d > 1) { int r_ = d-2; for (int v = L; v < g1; ++v) rank += CNK12[r_+7-v][r_]; L = g1; }
    if (d > 2) { int r_ = d-3; for (int v = L; v < g2; ++v) rank += CNK12[r_+7-v][r_]; L = g2; }
    if (d > 3) { int r_ = d-4; for (int v = L; v < g3; ++v) rank += CNK12[r_+7-v][r_]; L = g3; }
    if (d > 4) { rank += max(0, g4 - L); }
    int pos = atomicAdd(cnt + rank, 1);
    perm[rank * 120 + pos] = k;
    if (o0 == g0 && o1 == g1 && o2 == g2 && o3 == g3 && o4 == g4)
        digs[rank] = g0 | (g1 << 4) | (g2 << 8) | (g3 << 12) | (g4 << 16);
}

// 2 waves per rank (halved perm list), 4-deep independent loads, scalar perm
// reads. Block 256 = 4 waves = 2 ranks.
__global__ __launch_bounds__(256) void collapse(const float* __restrict__ WT,
                                                const float* __restrict__ bias,
                                                const int* __restrict__ cnt,
                                                const int* __restrict__ perm,
                                                _Float16* __restrict__ Wcf) {
    __shared__ float partial[4][64];
    int tid  = threadIdx.x;
    int lane = tid & 63;
    int wv   = tid >> 6;
    int rk   = __builtin_amdgcn_readfirstlane(blockIdx.x * 2 + (wv >> 1));
    int half = __builtin_amdgcn_readfirstlane(wv & 1);

    float acc = 0.f;
    if (rk < NRANK) {
        int nper = cnt[rk];
        const int* pl = perm + rk * 120;
        int i0 = half ? ((nper + 1) >> 1) : 0;
        int i1 = half ? nper : ((nper + 1) >> 1);
        float a0 = 0.f, a1 = 0.f, a2 = 0.f, a3 = 0.f;
        int i = i0;
        for (; i + 4 <= i1; i += 4) {
            int k0 = pl[i], k1 = pl[i+1], k2 = pl[i+2], k3 = pl[i+3];
            a0 += WT[(size_t)k0 * 64 + lane];
            a1 += WT[(size_t)k1 * 64 + lane];
            a2 += WT[(size_t)k2 * 64 + lane];
            a3 += WT[(size_t)k3 * 64 + lane];
        }
        for (; i < i1; ++i) a0 += WT[(size_t)pl[i] * 64 + lane];
        acc = (a0 + a1) + (a2 + a3);
    }
    partial[wv][lane] = acc;
    __syncthreads();
    if (half == 0 && rk < NRANK) {
        float tot = partial[wv][lane] + partial[wv + 1][lane];
        if (rk == 0) tot += bias[lane];
        // B-fragment: (s,nt,lane',j) = B[nt*16+(lane'&15)][s*32+(lane'>>4)*8+j]
        int s = rk >> 5, kk = rk & 31;
        int nt = lane >> 4, nl = lane & 15;
        Wcf[((size_t)(s * 4 + nt) * 64 + (kk >> 3) * 16 + nl) * 8 + (kk & 7)] =
            (_Float16)tot;
    }
}

// Fused: lane-parallel featgen (via digs) into LDS + 42-step MFMA GEMM.
__global__ __launch_bounds__(128) void feat_gemm(const float* __restrict__ z,
                                                 const _Float16* __restrict__ Wcf,
                                                 const int* __restrict__ digs,
                                                 float* __restrict__ out) {
    __shared__ _Float16 A[16][1352];      // pitch 1352 halfs (16B-aligned rows)
    __shared__ int dls[NRPAD];
    __shared__ _Float16 zls[16][17];      // rows 0..7 = z dims, row 8 = 1.0
    int tid = threadIdx.x;
    int m0  = blockIdx.x * 16;

    for (int i = tid; i < NRPAD; i += 128) dls[i] = digs[i];
    {
        int smp = tid >> 3, dd = tid & 7;
        zls[dd][smp] = (_Float16)z[(size_t)(m0 + smp) * 8 + dd];
    }
    if (tid < 16) zls[8][tid] = (_Float16)1.0f;
    __syncthreads();

    {   // featgen: thread (smp = tid&15, w = tid>>4) does ranks w, w+8, ...
        int smp = tid & 15, w = tid >> 4;
        _Float16* Am = &A[smp][0];
        for (int r = w; r < NRPAD; r += 8) {
            int dv = dls[r];
            _Float16 p = zls[dv & 15][smp] * zls[(dv >> 4) & 15][smp];
            p = p * zls[(dv >> 8) & 15][smp];
            p = p * zls[(dv >> 12) & 15][smp];
            p = p * zls[(dv >> 16) & 15][smp];
            Am[r] = (r < NRANK) ? p : (_Float16)0.f;
        }
    }
    __syncthreads();

    // GEMM: wave wv covers cols [wv*32, wv*32+32); 2 MFMA / step.
    int lane = tid & 63, wv = tid >> 6;
    int l16 = lane & 15, quad = lane >> 4;
    const _Float16* Arow  = &A[l16][quad * 8];
    const _Float16* Bbase = Wcf + (size_t)(2 * wv) * 512 + (size_t)lane * 8;

    f32x4 acc0 = (f32x4){0.f,0.f,0.f,0.f}, acc1 = (f32x4){0.f,0.f,0.f,0.f};
    auto ldA = [&](int s) { return *(const half8*)(Arow + s * 32); };
    auto ldB = [&](int s, half8* B) {
        B[0] = *(const half8*)(Bbase + (size_t)s * 2048);
        B[1] = *(const half8*)(Bbase + (size_t)s * 2048 + 512);
    };

    half8 Ab[4], Bb[4][2];
#pragma unroll
    for (int i = 0; i < 4; ++i) { Ab[i] = ldA(i); ldB(i, Bb[i]); }
#pragma unroll
    for (int s = 0; s < SPAD; ++s) {
        half8 a = Ab[s & 3], b0 = Bb[s & 3][0], b1 = Bb[s & 3][1];
        if (s + 4 < SPAD) { Ab[s & 3] = ldA(s + 4); ldB(s + 4, Bb[s & 3]); }
        acc0 = __builtin_amdgcn_mfma_f32_16x16x32_f16(a, b0, acc0, 0, 0, 0);
        acc1 = __builtin_amdgcn_mfma_f32_16x16x32_f16(a, b1, acc1, 0, 0, 0);
    }

    // C/D: col = lane&15, row = quad*4 + reg
#pragma unroll
    for (int nt = 0; nt < 2; ++nt) {
        f32x4 acc = nt ? acc1 : acc0;
        int col = wv * 32 + nt * 16 + l16;
#pragma unroll
        for (int r = 0; r < 4; ++r)
            out[(size_t)(m0 + quad * 4 + r) * 64 + col] = acc[r];
    }
}

extern "C" void kernel_launch(void* const* d_in, const int* in_sizes, int n_in,
                              void* d_out, int out_size, void* d_ws, size_t ws_size,
                              hipStream_t stream) {
    (void)in_sizes; (void)n_in; (void)out_size; (void)ws_size;
    const float* z = (const float*)d_in[0];
    const float* W = (const float*)d_in[1];
    const float* b = (const float*)d_in[2];
    float* out = (float*)d_out;

    _Float16* Wcf  = (_Float16*)d_ws;
    int*      cnt  = (int*)((char*)d_ws + CNT_OFF);
    int*      perm = (int*)((char*)d_ws + PERM_OFF);
    int*      digs = (int*)((char*)d_ws + DIGS_OFF);
    float*    WT   = (float*)((char*)d_ws + WT_OFF);   // 9,586,944 B

    hipMemsetAsync(d_ws, 0, PERM_OFF, stream);         // Wcf + cnt
    hipLaunchKernelGGL(prep, dim3(TB + RB), dim3(256), 0, stream,
                       W, WT, cnt, perm, digs);
    hipLaunchKernelGGL(collapse, dim3((NRANK + 1) / 2), dim3(256), 0, stream,
                       WT, b, cnt, perm, Wcf);
    hipLaunchKernelGGL(feat_gemm, dim3(4096 / 16), dim3(128), 0, stream,
                       z, Wcf, digs, out);
}

// Round 12
// 107.083 us; speedup vs baseline: 2.5444x; 1.0257x over previous
//
#include <hip/hip_runtime.h>

// ---------------------------------------------------------------------------
// PolyDecoder via SYMMETRY COLLAPSE:
//   out[4096,64] = A_mono[4096 x 1287] @ Wc^T   (bias folded into rank 0)
// A_mono = multiset monomials of z (deg<=5); Wc sums W over ordered tuples
// per multiset (29x FLOP reduction vs the ordered-Kronecker GEMM).
//
// Canonical order: degree-major, lex on sorted tuples. DOFF={0,1,9,45,165,495},
// NRANK=1287, padded to 1344 = 42 K32 steps. Digits packed 5x4 bits, pad=8
// (z~[8] := 1.0).
//
// Pipeline: memset(cnt) -> prep (transpose W->WT | rank/perm/digs)
//           -> collapse (block/rank, 4 waves x depth-8 masked gather)
//           -> feat_gemm (lane-parallel featgen via digs + 42-step MFMA GEMM).
// ---------------------------------------------------------------------------

#define K_TOT 37449
#define SPAD 42
#define NRANK 1287
#define NRPAD (SPAD * 32)                    // 1344
#define WCF_BYTES (SPAD * 4 * 64 * 8 * 2)    // 172032 (f16 B-fragments)
#define CNT_OFF   WCF_BYTES
#define CNT_BYTES 5248
#define PERM_OFF  (CNT_OFF + CNT_BYTES)      // 177280
#define DIGS_OFF  795136                     // past perm (617760)
#define WT_OFF    800512                     // past digs (5376); 16B-aligned

#define TB 586                               // transpose blocks (64 k each)
#define RB 147                               // rank blocks (256 k each)

typedef _Float16 half8 __attribute__((ext_vector_type(8)));
typedef float f32x4 __attribute__((ext_vector_type(4)));

__device__ __constant__ int CNK12[12][5] = {
    {1,0,0,0,0},{1,1,0,0,0},{1,2,1,0,0},{1,3,3,1,0},{1,4,6,4,1},
    {1,5,10,10,5},{1,6,15,20,15},{1,7,21,35,35},{1,8,28,56,70},
    {1,9,36,84,126},{1,10,45,120,210},{1,11,55,165,330}};

#define CE(x, y) { int lo_ = min(x, y), hi_ = max(x, y); x = lo_; y = hi_; }

// Dual-role: blocks [0,TB) transpose W[64][K]->WT[K][64]; blocks [TB,TB+RB)
// compute rank per k, append k to perm[rank], canonical k writes digs[rank].
__global__ __launch_bounds__(256) void prep(const float* __restrict__ W,
                                            float* __restrict__ WT,
                                            int* __restrict__ cnt,
                                            int* __restrict__ perm,
                                            int* __restrict__ digs) {
    __shared__ float t[64][65];
    int tid = threadIdx.x;
    int b   = blockIdx.x;

    if (b < TB) {
        int lane = tid & 63, nq = tid >> 6;
        int kb = b * 64;
#pragma unroll
        for (int r = 0; r < 16; ++r) {
            int n = nq * 16 + r;
            int k = kb + lane;
            t[n][lane] = (k < K_TOT) ? W[(size_t)n * K_TOT + k] : 0.f;
        }
        __syncthreads();
#pragma unroll
        for (int i = 0; i < 16; ++i) {
            int kk = nq * 16 + i;
            int k  = kb + kk;
            if (k < K_TOT) WT[(size_t)k * 64 + lane] = t[lane][kk];
        }
        return;
    }

    int k = (b - TB) * 256 + tid;
    if (k >= K_TOT) return;
    int d, k0 = 0;
    if (k == 0)        { d = 0; }
    else if (k < 9)    { d = 1; k0 = k - 1; }
    else if (k < 73)   { d = 2; k0 = k - 9; }
    else if (k < 585)  { d = 3; k0 = k - 73; }
    else if (k < 4681) { d = 4; k0 = k - 585; }
    else               { d = 5; k0 = k - 4681; }
    int g0 = 8, g1 = 8, g2 = 8, g3 = 8, g4 = 8;     // pad = 8
    if (d >= 1) { g0 = k0 & 7; k0 >>= 3; }
    if (d >= 2) { g1 = k0 & 7; k0 >>= 3; }
    if (d >= 3) { g2 = k0 & 7; k0 >>= 3; }
    if (d >= 4) { g3 = k0 & 7; k0 >>= 3; }
    if (d == 5) { g4 = k0 & 7; }
    int o0 = g0, o1 = g1, o2 = g2, o3 = g3, o4 = g4;
    CE(g0,g1); CE(g3,g4); CE(g2,g4); CE(g2,g3); CE(g1,g4);
    CE(g0,g3); CE(g0,g2); CE(g1,g3); CE(g1,g2);
    int rank = (d == 0) ? 0 : (d == 1) ? 1 : (d == 2) ? 9
             : (d == 3) ? 45 : (d == 4) ? 165 : 495;
    int L = 0;
    if (d > 0) { int r_ = d-1; for (int v = L; v < g0; ++v) rank += CNK12[r_+7-v][r_]; L = g0; }
    if (d > 1) { int r_ = d-2; for (int v = L; v < g1; ++v) rank += CNK12[r_+7-v][r_]; L = g1; }
    if (d > 2) { int r_ = d-3; for (int v = L; v < g2; ++v) rank += CNK12[r_+7-v][r_]; L = g2; }
    if (d > 3) { int r_ = d-4; for (int v = L; v < g3; ++v) rank += CNK12[r_+7-v][r_]; L = g3; }
    if (d > 4) { rank += max(0, g4 - L); }
    int pos = atomicAdd(cnt + rank, 1);
    perm[rank * 120 + pos] = k;
    if (o0 == g0 && o1 == g1 && o2 == g2 && o3 == g3 && o4 == g4)
        digs[rank] = g0 | (g1 << 4) | (g2 << 8) | (g3 << 12) | (g4 << 16);
}

// One block (4 waves) per rank. Wave wv gathers <=ceil(nper/4)<=30 entries
// with a masked depth-8 unroll (max 4 serial rounds — kills the 120-perm
// tail that bound R10/R11). LDS-combine, write f16 B-fragment.
__global__ __launch_bounds__(256) void collapse(const float* __restrict__ WT,
                                                const float* __restrict__ bias,
                                                const int* __restrict__ cnt,
                                                const int* __restrict__ perm,
                                                _Float16* __restrict__ Wcf) {
    __shared__ float partial[4][64];
    int tid  = threadIdx.x;
    int lane = tid & 63;
    int wv   = tid >> 6;
    int rk   = blockIdx.x;
    int nper = cnt[rk];                    // uniform
    const int* pl = perm + rk * 120;

    int q  = (nper + 3) >> 2;
    int c0 = wv * q;
    int c1 = min(nper, c0 + q);

    float a[8];
#pragma unroll
    for (int j = 0; j < 8; ++j) a[j] = 0.f;
    for (int i = c0; i < c1; i += 8) {
#pragma unroll
        for (int j = 0; j < 8; ++j) {
            int idx = min(i + j, c1 - 1);          // uniform, always valid
            int kk  = pl[idx];                     // scalar load
            float v = WT[(size_t)kk * 64 + lane];  // coalesced 256 B
            a[j] += (i + j < c1) ? v : 0.f;        // mask extras
        }
    }
    partial[wv][lane] = ((a[0]+a[1])+(a[2]+a[3])) + ((a[4]+a[5])+(a[6]+a[7]));
    __syncthreads();
    if (wv == 0) {
        float tot = partial[0][lane] + partial[1][lane]
                  + partial[2][lane] + partial[3][lane];
        if (rk == 0) tot += bias[lane];
        // B-fragment: (s,nt,lane',j) = B[nt*16+(lane'&15)][s*32+(lane'>>4)*8+j]
        int s = rk >> 5, kk2 = rk & 31;
        int nt = lane >> 4, nl = lane & 15;
        Wcf[((size_t)(s * 4 + nt) * 64 + (kk2 >> 3) * 16 + nl) * 8 + (kk2 & 7)] =
            (_Float16)tot;
    }
}

// Fused: lane-parallel featgen (via digs) into LDS + 42-step MFMA GEMM.
__global__ __launch_bounds__(128) void feat_gemm(const float* __restrict__ z,
                                                 const _Float16* __restrict__ Wcf,
                                                 const int* __restrict__ digs,
                                                 float* __restrict__ out) {
    __shared__ _Float16 A[16][1352];      // pitch 1352 halfs (16B-aligned rows)
    __shared__ int dls[NRPAD];
    __shared__ _Float16 zls[16][17];      // rows 0..7 = z dims, row 8 = 1.0
    int tid = threadIdx.x;
    int m0  = blockIdx.x * 16;

    for (int i = tid; i < NRPAD; i += 128) dls[i] = digs[i];
    {
        int smp = tid >> 3, dd = tid & 7;
        zls[dd][smp] = (_Float16)z[(size_t)(m0 + smp) * 8 + dd];
    }
    if (tid < 16) zls[8][tid] = (_Float16)1.0f;
    __syncthreads();

    {   // featgen: thread (smp = tid&15, w = tid>>4) does ranks w, w+8, ...
        int smp = tid & 15, w = tid >> 4;
        _Float16* Am = &A[smp][0];
        for (int r = w; r < NRPAD; r += 8) {
            int dv = dls[r];
            _Float16 p = zls[dv & 15][smp] * zls[(dv >> 4) & 15][smp];
            p = p * zls[(dv >> 8) & 15][smp];
            p = p * zls[(dv >> 12) & 15][smp];
            p = p * zls[(dv >> 16) & 15][smp];
            Am[r] = (r < NRANK) ? p : (_Float16)0.f;
        }
    }
    __syncthreads();

    // GEMM: wave wv covers cols [wv*32, wv*32+32); 2 MFMA / step.
    int lane = tid & 63, wv = tid >> 6;
    int l16 = lane & 15, quad = lane >> 4;
    const _Float16* Arow  = &A[l16][quad * 8];
    const _Float16* Bbase = Wcf + (size_t)(2 * wv) * 512 + (size_t)lane * 8;

    f32x4 acc0 = (f32x4){0.f,0.f,0.f,0.f}, acc1 = (f32x4){0.f,0.f,0.f,0.f};
    auto ldA = [&](int s) { return *(const half8*)(Arow + s * 32); };
    auto ldB = [&](int s, half8* B) {
        B[0] = *(const half8*)(Bbase + (size_t)s * 2048);
        B[1] = *(const half8*)(Bbase + (size_t)s * 2048 + 512);
    };

    half8 Ab[4], Bb[4][2];
#pragma unroll
    for (int i = 0; i < 4; ++i) { Ab[i] = ldA(i); ldB(i, Bb[i]); }
#pragma unroll
    for (int s = 0; s < SPAD; ++s) {
        half8 a = Ab[s & 3], b0 = Bb[s & 3][0], b1 = Bb[s & 3][1];
        if (s + 4 < SPAD) { Ab[s & 3] = ldA(s + 4); ldB(s + 4, Bb[s & 3]); }
        acc0 = __builtin_amdgcn_mfma_f32_16x16x32_f16(a, b0, acc0, 0, 0, 0);
        acc1 = __builtin_amdgcn_mfma_f32_16x16x32_f16(a, b1, acc1, 0, 0, 0);
    }

    // C/D: col = lane&15, row = quad*4 + reg
#pragma unroll
    for (int nt = 0; nt < 2; ++nt) {
        f32x4 acc = nt ? acc1 : acc0;
        int col = wv * 32 + nt * 16 + l16;
#pragma unroll
        for (int r = 0; r < 4; ++r)
            out[(size_t)(m0 + quad * 4 + r) * 64 + col] = acc[r];
    }
}

extern "C" void kernel_launch(void* const* d_in, const int* in_sizes, int n_in,
                              void* d_out, int out_size, void* d_ws, size_t ws_size,
                              hipStream_t stream) {
    (void)in_sizes; (void)n_in; (void)out_size; (void)ws_size;
    const float* z = (const float*)d_in[0];
    const float* W = (const float*)d_in[1];
    const float* b = (const float*)d_in[2];
    float* out = (float*)d_out;

    _Float16* Wcf  = (_Float16*)d_ws;
    int*      cnt  = (int*)((char*)d_ws + CNT_OFF);
    int*      perm = (int*)((char*)d_ws + PERM_OFF);
    int*      digs = (int*)((char*)d_ws + DIGS_OFF);
    float*    WT   = (float*)((char*)d_ws + WT_OFF);   // 9,586,944 B

    hipMemsetAsync(cnt, 0, CNT_BYTES, stream);         // counters only
    hipLaunchKernelGGL(prep, dim3(TB + RB), dim3(256), 0, stream,
                       W, WT, cnt, perm, digs);
    hipLaunchKernelGGL(collapse, dim3(NRANK), dim3(256), 0, stream,
                       WT, b, cnt, perm, Wcf);
    hipLaunchKernelGGL(feat_gemm, dim3(4096 / 16), dim3(128), 0, stream,
                       z, Wcf, digs, out);
}

// Round 13
// 100.138 us; speedup vs baseline: 2.7209x; 1.0694x over previous
//
#include <hip/hip_runtime.h>

// ---------------------------------------------------------------------------
// PolyDecoder via SYMMETRY COLLAPSE (fully atomic-free):
//   out[4096,64] = A_mono[4096 x 1287] @ Wc^T   (bias folded into rank 0)
// A_mono = multiset monomials of z (deg<=5); Wc sums W over ordered tuples
// per multiset (29x FLOP reduction vs the ordered-Kronecker GEMM).
//
// Canonical order: degree-major, lex on sorted tuples. DOFF={0,1,9,45,165,495},
// NRANK=1287, padded to 1344 = 42 K32 steps. Digits packed 5x4 bits, pad=8
// (z~[8] := 1.0).
//
// Key R13 change: perm-list position = multinomial lex index of k's tuple
// within its multiset (pure function of k) -> plain scatter stores, ZERO
// atomics (R12's contended returning atomicAdd was the hidden ~35 us).
//
// Pipeline: prep (transpose W->WT | rank/pos/digs/cnt) -> collapse
//           (block/rank gather, 4 waves x depth-8 masked) -> feat_gemm.
// ---------------------------------------------------------------------------

#define K_TOT 37449
#define SPAD 42
#define NRANK 1287
#define NRPAD (SPAD * 32)                    // 1344
#define WCF_BYTES (SPAD * 4 * 64 * 8 * 2)    // 172032 (f16 B-fragments)
#define CNT_OFF   WCF_BYTES
#define CNT_BYTES 5248
#define PERM_OFF  (CNT_OFF + CNT_BYTES)      // 177280
#define DIGS_OFF  795136                     // past perm (617760)
#define WT_OFF    800512                     // past digs (5376); 16B-aligned

#define TB 586                               // transpose blocks (64 k each)
#define RB 147                               // rank blocks (256 k each)

typedef _Float16 half8 __attribute__((ext_vector_type(8)));
typedef float f32x4 __attribute__((ext_vector_type(4)));

__device__ __constant__ int CNK12[12][5] = {
    {1,0,0,0,0},{1,1,0,0,0},{1,2,1,0,0},{1,3,3,1,0},{1,4,6,4,1},
    {1,5,10,10,5},{1,6,15,20,15},{1,7,21,35,35},{1,8,28,56,70},
    {1,9,36,84,126},{1,10,45,120,210},{1,11,55,165,330}};
__device__ __constant__ int FACT[6] = {1, 1, 2, 6, 24, 120};

#define CE(x, y) { int lo_ = min(x, y), hi_ = max(x, y); x = lo_; y = hi_; }

// Dual-role: blocks [0,TB) transpose W[64][K]->WT[K][64]; blocks [TB,TB+RB):
// per k compute (rank, pos) and scatter-store k into perm; canonical k also
// stores digs[rank] and cnt[rank]=nperm. No atomics.
__global__ __launch_bounds__(256) void prep(const float* __restrict__ W,
                                            float* __restrict__ WT,
                                            int* __restrict__ cnt,
                                            int* __restrict__ perm,
                                            int* __restrict__ digs) {
    __shared__ float t[64][65];
    int tid = threadIdx.x;
    int b   = blockIdx.x;

    if (b < TB) {
        int lane = tid & 63, nq = tid >> 6;
        int kb = b * 64;
#pragma unroll
        for (int r = 0; r < 16; ++r) {
            int n = nq * 16 + r;
            int k = kb + lane;
            t[n][lane] = (k < K_TOT) ? W[(size_t)n * K_TOT + k] : 0.f;
        }
        __syncthreads();
#pragma unroll
        for (int i = 0; i < 16; ++i) {
            int kk = nq * 16 + i;
            int k  = kb + kk;
            if (k < K_TOT) WT[(size_t)k * 64 + lane] = t[lane][kk];
        }
        return;
    }

    int k = (b - TB) * 256 + tid;
    if (k >= K_TOT) return;
    int d, k0 = 0;
    if (k == 0)        { d = 0; }
    else if (k < 9)    { d = 1; k0 = k - 1; }
    else if (k < 73)   { d = 2; k0 = k - 9; }
    else if (k < 585)  { d = 3; k0 = k - 73; }
    else if (k < 4681) { d = 4; k0 = k - 585; }
    else               { d = 5; k0 = k - 4681; }

    // digits (little-endian tuple order), pad = 8 for sorted form
    int a0 = (d > 0) ? (k0 & 7) : 8;
    int a1 = (d > 1) ? ((k0 >> 3) & 7) : 8;
    int a2 = (d > 2) ? ((k0 >> 6) & 7) : 8;
    int a3 = (d > 3) ? ((k0 >> 9) & 7) : 8;
    int a4 = (d > 4) ? ((k0 >> 12) & 7) : 8;

    int g0 = a0, g1 = a1, g2 = a2, g3 = a3, g4 = a4;
    CE(g0,g1); CE(g3,g4); CE(g2,g4); CE(g2,g3); CE(g1,g4);
    CE(g0,g3); CE(g0,g2); CE(g1,g3); CE(g1,g2);

    // ---- rank (degree-major, lex on sorted tuple) ----
    int rank = (d == 0) ? 0 : (d == 1) ? 1 : (d == 2) ? 9
             : (d == 3) ? 45 : (d == 4) ? 165 : 495;
    int L = 0;
    if (d > 0) { int r_ = d-1; for (int v = L; v < g0; ++v) rank += CNK12[r_+7-v][r_]; L = g0; }
    if (d > 1) { int r_ = d-2; for (int v = L; v < g1; ++v) rank += CNK12[r_+7-v][r_]; L = g1; }
    if (d > 2) { int r_ = d-3; for (int v = L; v < g2; ++v) rank += CNK12[r_+7-v][r_]; L = g2; }
    if (d > 3) { int r_ = d-4; for (int v = L; v < g3; ++v) rank += CNK12[r_+7-v][r_]; L = g3; }
    if (d > 4) { rank += max(0, g4 - L); }

    // ---- pos: multinomial lex index of tuple among its multiset perms ----
    unsigned pk = 0;                       // counts packed 4 bits per symbol
    int adig[5] = {a0, a1, a2, a3, a4};
#pragma unroll
    for (int i = 0; i < 5; ++i)
        if (i < d) pk += 1u << (4 * adig[i]);

    int pos = 0;
#pragma unroll
    for (int i = 0; i < 5; ++i) {
        if (i >= d) break;
        int ai = adig[i];
        int m = d - 1 - i;                 // items remaining after slot i
        for (int v = 0; v < ai; ++v) {
            int cv = (pk >> (4 * v)) & 15;
            if (cv > 0) {
                unsigned pk2 = pk - (1u << (4 * v));
                int den = 1;
#pragma unroll
                for (int u = 0; u < 8; ++u) den *= FACT[(pk2 >> (4 * u)) & 15];
                pos += FACT[m] / den;
            }
        }
        pk -= 1u << (4 * ai);
    }

    perm[rank * 120 + pos] = k;            // plain scatter store

    if (a0 == g0 && a1 == g1 && a2 == g2 && a3 == g3 && a4 == g4) {
        // canonical representative: write digits + permutation count
        digs[rank] = g0 | (g1 << 4) | (g2 << 8) | (g3 << 12) | (g4 << 16);
        int den = 1;
#pragma unroll
        for (int i = 0; i < 5; ++i)
            if (i < d) den *= FACT[(pk >> (4 * adig[i])) & 15];  // pk now 0; recompute
        // recompute counts for nperm
        unsigned pk3 = 0;
#pragma unroll
        for (int i = 0; i < 5; ++i)
            if (i < d) pk3 += 1u << (4 * adig[i]);
        den = 1;
#pragma unroll
        for (int u = 0; u < 8; ++u) den *= FACT[(pk3 >> (4 * u)) & 15];
        cnt[rank] = FACT[d] / den;
    }
}

// One block (4 waves) per rank. Wave wv gathers <=ceil(nper/4)<=30 entries
// with a masked depth-8 unroll. LDS-combine, write f16 B-fragment.
__global__ __launch_bounds__(256) void collapse(const float* __restrict__ WT,
                                                const float* __restrict__ bias,
                                                const int* __restrict__ cnt,
                                                const int* __restrict__ perm,
                                                _Float16* __restrict__ Wcf) {
    __shared__ float partial[4][64];
    int tid  = threadIdx.x;
    int lane = tid & 63;
    int wv   = tid >> 6;
    int rk   = blockIdx.x;
    int nper = cnt[rk];                    // uniform
    const int* pl = perm + rk * 120;

    int q  = (nper + 3) >> 2;
    int c0 = wv * q;
    int c1 = min(nper, c0 + q);

    float a[8];
#pragma unroll
    for (int j = 0; j < 8; ++j) a[j] = 0.f;
    for (int i = c0; i < c1; i += 8) {
#pragma unroll
        for (int j = 0; j < 8; ++j) {
            int idx = min(i + j, c1 - 1);          // uniform, always valid
            int kk  = pl[idx];                     // scalar load
            float v = WT[(size_t)kk * 64 + lane];  // coalesced 256 B
            a[j] += (i + j < c1) ? v : 0.f;        // mask extras
        }
    }
    partial[wv][lane] = ((a[0]+a[1])+(a[2]+a[3])) + ((a[4]+a[5])+(a[6]+a[7]));
    __syncthreads();
    if (wv == 0) {
        float tot = partial[0][lane] + partial[1][lane]
                  + partial[2][lane] + partial[3][lane];
        if (rk == 0) tot += bias[lane];
        // B-fragment: (s,nt,lane',j) = B[nt*16+(lane'&15)][s*32+(lane'>>4)*8+j]
        int s = rk >> 5, kk2 = rk & 31;
        int nt = lane >> 4, nl = lane & 15;
        Wcf[((size_t)(s * 4 + nt) * 64 + (kk2 >> 3) * 16 + nl) * 8 + (kk2 & 7)] =
            (_Float16)tot;
    }
}

// Fused: lane-parallel featgen (via digs) into LDS + 42-step MFMA GEMM.
__global__ __launch_bounds__(128) void feat_gemm(const float* __restrict__ z,
                                                 const _Float16* __restrict__ Wcf,
                                                 const int* __restrict__ digs,
                                                 float* __restrict__ out) {
    __shared__ _Float16 A[16][1352];      // pitch 1352 halfs (16B-aligned rows)
    __shared__ int dls[NRPAD];
    __shared__ _Float16 zls[16][17];      // rows 0..7 = z dims, row 8 = 1.0
    int tid = threadIdx.x;
    int m0  = blockIdx.x * 16;

    for (int i = tid; i < NRPAD; i += 128) dls[i] = digs[i];
    {
        int smp = tid >> 3, dd = tid & 7;
        zls[dd][smp] = (_Float16)z[(size_t)(m0 + smp) * 8 + dd];
    }
    if (tid < 16) zls[8][tid] = (_Float16)1.0f;
    __syncthreads();

    {   // featgen: thread (smp = tid&15, w = tid>>4) does ranks w, w+8, ...
        int smp = tid & 15, w = tid >> 4;
        _Float16* Am = &A[smp][0];
        for (int r = w; r < NRPAD; r += 8) {
            int dv = dls[r];
            _Float16 p = zls[dv & 15][smp] * zls[(dv >> 4) & 15][smp];
            p = p * zls[(dv >> 8) & 15][smp];
            p = p * zls[(dv >> 12) & 15][smp];
            p = p * zls[(dv >> 16) & 15][smp];
            Am[r] = (r < NRANK) ? p : (_Float16)0.f;
        }
    }
    __syncthreads();

    // GEMM: wave wv covers cols [wv*32, wv*32+32); 2 MFMA / step.
    int lane = tid & 63, wv = tid >> 6;
    int l16 = lane & 15, quad = lane >> 4;
    const _Float16* Arow  = &A[l16][quad * 8];
    const _Float16* Bbase = Wcf + (size_t)(2 * wv) * 512 + (size_t)lane * 8;

    f32x4 acc0 = (f32x4){0.f,0.f,0.f,0.f}, acc1 = (f32x4){0.f,0.f,0.f,0.f};
    auto ldA = [&](int s) { return *(const half8*)(Arow + s * 32); };
    auto ldB = [&](int s, half8* B) {
        B[0] = *(const half8*)(Bbase + (size_t)s * 2048);
        B[1] = *(const half8*)(Bbase + (size_t)s * 2048 + 512);
    };

    half8 Ab[4], Bb[4][2];
#pragma unroll
    for (int i = 0; i < 4; ++i) { Ab[i] = ldA(i); ldB(i, Bb[i]); }
#pragma unroll
    for (int s = 0; s < SPAD; ++s) {
        half8 a = Ab[s & 3], b0 = Bb[s & 3][0], b1 = Bb[s & 3][1];
        if (s + 4 < SPAD) { Ab[s & 3] = ldA(s + 4); ldB(s + 4, Bb[s & 3]); }
        acc0 = __builtin_amdgcn_mfma_f32_16x16x32_f16(a, b0, acc0, 0, 0, 0);
        acc1 = __builtin_amdgcn_mfma_f32_16x16x32_f16(a, b1, acc1, 0, 0, 0);
    }

    // C/D: col = lane&15, row = quad*4 + reg
#pragma unroll
    for (int nt = 0; nt < 2; ++nt) {
        f32x4 acc = nt ? acc1 : acc0;
        int col = wv * 32 + nt * 16 + l16;
#pragma unroll
        for (int r = 0; r < 4; ++r)
            out[(size_t)(m0 + quad * 4 + r) * 64 + col] = acc[r];
    }
}

extern "C" void kernel_launch(void* const* d_in, const int* in_sizes, int n_in,
                              void* d_out, int out_size, void* d_ws, size_t ws_size,
                              hipStream_t stream) {
    (void)in_sizes; (void)n_in; (void)out_size; (void)ws_size;
    const float* z = (const float*)d_in[0];
    const float* W = (const float*)d_in[1];
    const float* b = (const float*)d_in[2];
    float* out = (float*)d_out;

    _Float16* Wcf  = (_Float16*)d_ws;
    int*      cnt  = (int*)((char*)d_ws + CNT_OFF);
    int*      perm = (int*)((char*)d_ws + PERM_OFF);
    int*      digs = (int*)((char*)d_ws + DIGS_OFF);
    float*    WT   = (float*)((char*)d_ws + WT_OFF);   // 9,586,944 B

    hipLaunchKernelGGL(prep, dim3(TB + RB), dim3(256), 0, stream,
                       W, WT, cnt, perm, digs);
    hipLaunchKernelGGL(collapse, dim3(NRANK), dim3(256), 0, stream,
                       WT, b, cnt, perm, Wcf);
    hipLaunchKernelGGL(feat_gemm, dim3(4096 / 16), dim3(128), 0, stream,
                       z, Wcf, digs, out);
}